// Round 1
// baseline (1050.479 us; speedup 1.0000x reference)
//
#include <hip/hip_runtime.h>

#define D_MODEL 1024
#define NHEADS  16
#define DEPTH   64
#define BB      2
#define SS      2048
#define MROWS   (BB*SS)     // 4096
#define BHN     (BB*NHEADS) // 32

using f16 = _Float16;
using f16x8 = __attribute__((ext_vector_type(8))) _Float16;
using f32x4 = __attribute__((ext_vector_type(4))) float;

__device__ __forceinline__ void g2l16(const void* g, void* l) {
  __builtin_amdgcn_global_load_lds(
      (const __attribute__((address_space(1))) void*)g,
      (__attribute__((address_space(3))) void*)l, 16, 0, 0);
}

// ---- fp32 W[k][n] -> f16 Wt[n][k], 4 matrices via grid.z ----
__global__ __launch_bounds__(256) void wtrans(
    const float* __restrict__ w0, const float* __restrict__ w1,
    const float* __restrict__ w2, const float* __restrict__ w3,
    f16* __restrict__ wt) {
  const float* W = blockIdx.z == 0 ? w0 : blockIdx.z == 1 ? w1 : blockIdx.z == 2 ? w2 : w3;
  f16* Wt = wt + (size_t)blockIdx.z * D_MODEL * D_MODEL;
  __shared__ float tile[64][65];
  const int t = threadIdx.x;
  const int bx = blockIdx.x * 64, by = blockIdx.y * 64;
  const int c = t & 63, r0 = t >> 6;
#pragma unroll
  for (int i = 0; i < 16; ++i) {
    int r = r0 + i * 4;
    tile[r][c] = W[(size_t)(by + r) * D_MODEL + bx + c];
  }
  __syncthreads();
#pragma unroll
  for (int i = 0; i < 16; ++i) {
    int r = r0 + i * 4;
    Wt[(size_t)(bx + r) * D_MODEL + by + c] = (f16)tile[c][r];
  }
}

// ---- Q/K/V projection: A(fp32 4096x1024) @ Wt^T + bias -> heads f16 [b,h,s,64] ----
__global__ __launch_bounds__(256) void proj_gemm(
    const float* __restrict__ Q, const float* __restrict__ K, const float* __restrict__ V,
    const f16* __restrict__ Wt,
    const float* __restrict__ bq, const float* __restrict__ bk, const float* __restrict__ bv,
    f16* __restrict__ heads) {
  const int z = blockIdx.z;
  const float* A = z == 0 ? Q : z == 1 ? K : V;
  const f16* Bt = Wt + (size_t)z * D_MODEL * D_MODEL;
  const float* bias = z == 0 ? bq : z == 1 ? bk : bv;
  f16* dst = heads + (size_t)z * MROWS * D_MODEL;

  __shared__ f16 As[128 * 32];
  __shared__ f16 Bs[128 * 32];
  const int t = threadIdx.x, lane = t & 63, w = t >> 6;
  const int m0 = blockIdx.y * 128, n0 = blockIdx.x * 128;
  const int wr = (w >> 1) * 64, wc = (w & 1) * 64;
  f32x4 acc[4][4] = {};

  for (int k0 = 0; k0 < D_MODEL; k0 += 32) {
    __syncthreads();
#pragma unroll
    for (int i = 0; i < 4; ++i) {             // A: 128x32 fp32 -> f16 LDS
      int f = t + i * 256;
      int row = f >> 3, c4 = (f & 7) * 4;
      const float4 v4 = *(const float4*)(A + (size_t)(m0 + row) * D_MODEL + k0 + c4);
      f16* p = &As[row * 32 + c4];
      p[0] = (f16)v4.x; p[1] = (f16)v4.y; p[2] = (f16)v4.z; p[3] = (f16)v4.w;
    }
#pragma unroll
    for (int i = 0; i < 2; ++i) {             // B: 128x32 f16 via global_load_lds
      int seg = t + i * 256;
      int row = seg >> 2, c8 = (seg & 3) * 8;
      g2l16(Bt + (size_t)(n0 + row) * D_MODEL + k0 + c8, &Bs[seg * 8]);
    }
    __syncthreads();
    f16x8 af[4], bfr[4];
#pragma unroll
    for (int i = 0; i < 4; ++i)
      af[i] = *(const f16x8*)&As[(wr + i * 16 + (lane & 15)) * 32 + (lane >> 4) * 8];
#pragma unroll
    for (int j = 0; j < 4; ++j)
      bfr[j] = *(const f16x8*)&Bs[(wc + j * 16 + (lane & 15)) * 32 + (lane >> 4) * 8];
#pragma unroll
    for (int i = 0; i < 4; ++i)
#pragma unroll
      for (int j = 0; j < 4; ++j)
        acc[i][j] = __builtin_amdgcn_mfma_f32_16x16x32_f16(af[i], bfr[j], acc[i][j], 0, 0, 0);
  }
#pragma unroll
  for (int i = 0; i < 4; ++i)
#pragma unroll
    for (int j = 0; j < 4; ++j) {
      int n = n0 + wc + j * 16 + (lane & 15);
      float bn = bias[n];
      int h = n >> 6, d = n & 63;
#pragma unroll
      for (int r = 0; r < 4; ++r) {
        int m = m0 + wr + i * 16 + (lane >> 4) * 4 + r;
        int b = m >> 11, s = m & 2047;
        dst[((size_t)(b * NHEADS + h) * SS + s) * DEPTH + d] = (f16)(acc[i][j][r] + bn);
      }
    }
}

// ---- scores: per (b,h) q @ k^T * 0.125 + mask -> fp32 attn region ----
__global__ __launch_bounds__(256) void scores_gemm(
    const f16* __restrict__ qh, const f16* __restrict__ kh,
    const float* __restrict__ mask, float* __restrict__ attn) {
  const int bh = blockIdx.z, b = bh >> 4;
  const f16* A = qh + (size_t)bh * SS * DEPTH;
  const f16* Bt = kh + (size_t)bh * SS * DEPTH;
  float* out = attn + (size_t)bh * SS * SS;

  __shared__ f16 As[128 * 32];
  __shared__ f16 Bs[128 * 32];
  const int t = threadIdx.x, lane = t & 63, w = t >> 6;
  const int m0 = blockIdx.y * 128, n0 = blockIdx.x * 128;
  const int wr = (w >> 1) * 64, wc = (w & 1) * 64;
  f32x4 acc[4][4] = {};

  for (int k0 = 0; k0 < DEPTH; k0 += 32) {
    __syncthreads();
#pragma unroll
    for (int i = 0; i < 2; ++i) {
      int seg = t + i * 256;
      int row = seg >> 2, c8 = (seg & 3) * 8;
      g2l16(A + (size_t)(m0 + row) * DEPTH + k0 + c8, &As[seg * 8]);
      g2l16(Bt + (size_t)(n0 + row) * DEPTH + k0 + c8, &Bs[seg * 8]);
    }
    __syncthreads();
    f16x8 af[4], bfr[4];
#pragma unroll
    for (int i = 0; i < 4; ++i)
      af[i] = *(const f16x8*)&As[(wr + i * 16 + (lane & 15)) * 32 + (lane >> 4) * 8];
#pragma unroll
    for (int j = 0; j < 4; ++j)
      bfr[j] = *(const f16x8*)&Bs[(wc + j * 16 + (lane & 15)) * 32 + (lane >> 4) * 8];
#pragma unroll
    for (int i = 0; i < 4; ++i)
#pragma unroll
      for (int j = 0; j < 4; ++j)
        acc[i][j] = __builtin_amdgcn_mfma_f32_16x16x32_f16(af[i], bfr[j], acc[i][j], 0, 0, 0);
  }
#pragma unroll
  for (int i = 0; i < 4; ++i)
#pragma unroll
    for (int j = 0; j < 4; ++j) {
      int n = n0 + wc + j * 16 + (lane & 15);
      float mv = mask[b * SS + n] * (-1e9f);
#pragma unroll
      for (int r = 0; r < 4; ++r) {
        int m = m0 + wr + i * 16 + (lane >> 4) * 4 + r;
        out[(size_t)m * SS + n] = acc[i][j][r] * 0.125f + mv;
      }
    }
}

// ---- row softmax in place, one block per row of 2048 ----
__global__ __launch_bounds__(256) void softmax_rows(float* __restrict__ attn) {
  float* row = attn + (size_t)blockIdx.x * SS;
  const int t = threadIdx.x;
  float4 a = ((const float4*)row)[t];
  float4 b = ((const float4*)row)[t + 256];
  float mx = fmaxf(fmaxf(fmaxf(a.x, a.y), fmaxf(a.z, a.w)),
                   fmaxf(fmaxf(b.x, b.y), fmaxf(b.z, b.w)));
#pragma unroll
  for (int o = 32; o > 0; o >>= 1) mx = fmaxf(mx, __shfl_xor(mx, o, 64));
  __shared__ float redm[4], reds[4];
  if ((t & 63) == 0) redm[t >> 6] = mx;
  __syncthreads();
  mx = fmaxf(fmaxf(redm[0], redm[1]), fmaxf(redm[2], redm[3]));
  a.x = __expf(a.x - mx); a.y = __expf(a.y - mx); a.z = __expf(a.z - mx); a.w = __expf(a.w - mx);
  b.x = __expf(b.x - mx); b.y = __expf(b.y - mx); b.z = __expf(b.z - mx); b.w = __expf(b.w - mx);
  float sm = a.x + a.y + a.z + a.w + b.x + b.y + b.z + b.w;
#pragma unroll
  for (int o = 32; o > 0; o >>= 1) sm += __shfl_xor(sm, o, 64);
  if ((t & 63) == 0) reds[t >> 6] = sm;
  __syncthreads();
  sm = reds[0] + reds[1] + reds[2] + reds[3];
  float inv = 1.0f / sm;
  a.x *= inv; a.y *= inv; a.z *= inv; a.w *= inv;
  b.x *= inv; b.y *= inv; b.z *= inv; b.w *= inv;
  ((float4*)row)[t] = a;
  ((float4*)row)[t + 256] = b;
}

// ---- attn(fp32) @ v -> outh f16 [b][s][h*64+d]; tile 256x64, K=2048 ----
__global__ __launch_bounds__(256) void pv_gemm(
    const float* __restrict__ attn, const f16* __restrict__ vh, f16* __restrict__ outh) {
  const int bh = blockIdx.y, b = bh >> 4, h = bh & 15;
  const float* A = attn + (size_t)bh * SS * SS;
  const f16* Vh = vh + (size_t)bh * SS * DEPTH;
  const int m0 = blockIdx.x * 256;
  __shared__ f16 As[256 * 32];
  __shared__ f16 Bs[64 * 32];
  const int t = threadIdx.x, lane = t & 63, w = t >> 6;
  f32x4 acc[4][4] = {};

  for (int k0 = 0; k0 < SS; k0 += 32) {
    __syncthreads();
#pragma unroll
    for (int i = 0; i < 8; ++i) {             // A: 256x32 fp32 -> f16
      int f = t + i * 256;
      int row = f >> 3, c4 = (f & 7) * 4;
      const float4 v4 = *(const float4*)(A + (size_t)(m0 + row) * SS + k0 + c4);
      f16* p = &As[row * 32 + c4];
      p[0] = (f16)v4.x; p[1] = (f16)v4.y; p[2] = (f16)v4.z; p[3] = (f16)v4.w;
    }
#pragma unroll
    for (int i = 0; i < 2; ++i) {             // V tile 32k x 64d -> Bs[d][k]
      int f = t + i * 256;
      int kk = f >> 4, d4 = (f & 15) * 4;
      const f16* src = Vh + (size_t)(k0 + kk) * DEPTH + d4;
      f16 v0 = src[0], v1 = src[1], v2 = src[2], v3 = src[3];
      Bs[(d4 + 0) * 32 + kk] = v0; Bs[(d4 + 1) * 32 + kk] = v1;
      Bs[(d4 + 2) * 32 + kk] = v2; Bs[(d4 + 3) * 32 + kk] = v3;
    }
    __syncthreads();
    f16x8 af[4], bfr[4];
#pragma unroll
    for (int i = 0; i < 4; ++i)
      af[i] = *(const f16x8*)&As[(w * 64 + i * 16 + (lane & 15)) * 32 + (lane >> 4) * 8];
#pragma unroll
    for (int j = 0; j < 4; ++j)
      bfr[j] = *(const f16x8*)&Bs[(j * 16 + (lane & 15)) * 32 + (lane >> 4) * 8];
#pragma unroll
    for (int i = 0; i < 4; ++i)
#pragma unroll
      for (int j = 0; j < 4; ++j)
        acc[i][j] = __builtin_amdgcn_mfma_f32_16x16x32_f16(af[i], bfr[j], acc[i][j], 0, 0, 0);
  }
#pragma unroll
  for (int i = 0; i < 4; ++i)
#pragma unroll
    for (int j = 0; j < 4; ++j) {
      int d = j * 16 + (lane & 15);
#pragma unroll
      for (int r = 0; r < 4; ++r) {
        int s = m0 + w * 64 + i * 16 + (lane >> 4) * 4 + r;
        outh[((size_t)b * SS + s) * D_MODEL + h * DEPTH + d] = (f16)acc[i][j][r];
      }
    }
}

// ---- out = outh(f16 4096x1024) @ Wo^T + bo -> fp32 d_out ----
__global__ __launch_bounds__(256) void final_gemm(
    const f16* __restrict__ A, const f16* __restrict__ Bt,
    const float* __restrict__ bias, float* __restrict__ out) {
  __shared__ f16 As[128 * 32];
  __shared__ f16 Bs[128 * 32];
  const int t = threadIdx.x, lane = t & 63, w = t >> 6;
  const int m0 = blockIdx.y * 128, n0 = blockIdx.x * 128;
  const int wr = (w >> 1) * 64, wc = (w & 1) * 64;
  f32x4 acc[4][4] = {};

  for (int k0 = 0; k0 < D_MODEL; k0 += 32) {
    __syncthreads();
#pragma unroll
    for (int i = 0; i < 2; ++i) {
      int seg = t + i * 256;
      int row = seg >> 2, c8 = (seg & 3) * 8;
      g2l16(A + (size_t)(m0 + row) * D_MODEL + k0 + c8, &As[seg * 8]);
      g2l16(Bt + (size_t)(n0 + row) * D_MODEL + k0 + c8, &Bs[seg * 8]);
    }
    __syncthreads();
    f16x8 af[4], bfr[4];
#pragma unroll
    for (int i = 0; i < 4; ++i)
      af[i] = *(const f16x8*)&As[(wr + i * 16 + (lane & 15)) * 32 + (lane >> 4) * 8];
#pragma unroll
    for (int j = 0; j < 4; ++j)
      bfr[j] = *(const f16x8*)&Bs[(wc + j * 16 + (lane & 15)) * 32 + (lane >> 4) * 8];
#pragma unroll
    for (int i = 0; i < 4; ++i)
#pragma unroll
      for (int j = 0; j < 4; ++j)
        acc[i][j] = __builtin_amdgcn_mfma_f32_16x16x32_f16(af[i], bfr[j], acc[i][j], 0, 0, 0);
  }
#pragma unroll
  for (int i = 0; i < 4; ++i)
#pragma unroll
    for (int j = 0; j < 4; ++j) {
      int n = n0 + wc + j * 16 + (lane & 15);
      float bn = bias[n];
#pragma unroll
      for (int r = 0; r < 4; ++r) {
        int m = m0 + wr + i * 16 + (lane >> 4) * 4 + r;
        out[(size_t)m * D_MODEL + n] = acc[i][j][r] + bn;
      }
    }
}

extern "C" void kernel_launch(void* const* d_in, const int* in_sizes, int n_in,
                              void* d_out, int out_size, void* d_ws, size_t ws_size,
                              hipStream_t stream) {
  const float* Q    = (const float*)d_in[0];
  const float* K    = (const float*)d_in[1];
  const float* V    = (const float*)d_in[2];
  const float* mask = (const float*)d_in[3];
  const float* Wq   = (const float*)d_in[4];
  const float* bq   = (const float*)d_in[5];
  const float* Wk   = (const float*)d_in[6];
  const float* bk   = (const float*)d_in[7];
  const float* Wv   = (const float*)d_in[8];
  const float* bv   = (const float*)d_in[9];
  const float* Wo   = (const float*)d_in[10];
  const float* bo   = (const float*)d_in[11];

  float* out0 = (float*)d_out;
  float* attn = out0 + (size_t)MROWS * D_MODEL;   // output 1 region

  char* ws = (char*)d_ws;
  f16* Wt    = (f16*)ws;                                   // 4 x 1M f16  =  8 MB
  f16* heads = (f16*)(ws + (size_t)8 * 1024 * 1024);       // 3 x 4M f16  = 24 MB
  f16* outh  = (f16*)(ws + (size_t)32 * 1024 * 1024);      // 4M f16      =  8 MB
  f16* qh = heads;
  f16* kh = heads + (size_t)MROWS * D_MODEL;
  f16* vh = heads + (size_t)2 * MROWS * D_MODEL;

  wtrans<<<dim3(16, 16, 4), 256, 0, stream>>>(Wq, Wk, Wv, Wo, Wt);
  proj_gemm<<<dim3(8, 32, 3), 256, 0, stream>>>(Q, K, V, Wt, bq, bk, bv, heads);
  scores_gemm<<<dim3(16, 16, BHN), 256, 0, stream>>>(qh, kh, mask, attn);
  softmax_rows<<<dim3(BHN * SS), 256, 0, stream>>>(attn);
  pv_gemm<<<dim3(8, BHN), 256, 0, stream>>>(attn, vh, outh);
  final_gemm<<<dim3(8, 32), 256, 0, stream>>>(outh, Wt + (size_t)3 * D_MODEL * D_MODEL, bo, out0);
}